// Round 15
// baseline (1110.999 us; speedup 1.0000x reference)
//
#include <hip/hip_runtime.h>
#include <math.h>

#define S 32
#define T 32
#define B 64
#define H 256
#define MSZ 65536   // elements per swizzled bf16 matrix [8 kt][256 col][32 kk]
#define ROWSP 16

typedef __attribute__((ext_vector_type(8))) short s16x8;
typedef __attribute__((ext_vector_type(4))) float f32x4;

__device__ inline unsigned short f2b(float f){
    unsigned u = __builtin_bit_cast(unsigned, f);
    u += 0x7fffu + ((u >> 16) & 1u);          // RNE
    return (unsigned short)(u >> 16);
}
__device__ inline float b2f(unsigned short s){
    unsigned u = ((unsigned)s) << 16;
    return __builtin_bit_cast(float, u);
}
__device__ inline float tanh_fast(float x){
    float e = __builtin_amdgcn_exp2f(x * 2.8853900817779268f);
    float r = __builtin_amdgcn_rcpf(e + 1.0f);
    return fmaf(-2.0f, r, 1.0f);
}
// executed by ALL waves: uniform-address spin; per-wave acquire on exit
__device__ inline void waitflag(int* f, int target){
    while (__hip_atomic_load(f, __ATOMIC_RELAXED, __HIP_MEMORY_SCOPE_AGENT) < target)
        __builtin_amdgcn_s_sleep(2);
    (void)__hip_atomic_load(f, __ATOMIC_ACQUIRE, __HIP_MEMORY_SCOPE_AGENT);
}

// ---------------- prep: swizzle U (both depths, top/left) + W[1] to bf16 ----
// Bsw[m][kt][c][kk] = M_m[kt*32+kk][c];  m: 0=U0t 1=U0l 2=U1t 3=U1l 4=W1
__global__ __launch_bounds__(256) void prep_kernel(
    const float* __restrict__ U, const float* __restrict__ W,
    unsigned short* __restrict__ Bsw)
{
    int t = blockIdx.x * 256 + threadIdx.x;
    if (t >= 5 * MSZ) return;
    int m  = t >> 16;
    int r  = t & 65535;
    int kt = r >> 13;
    int r2 = r & 8191;
    int c  = r2 >> 5;
    int kk = r2 & 31;
    int krow = kt * 32 + kk;
    float v;
    if (m < 4){ int d = m >> 1, ope = m & 1; v = U[((size_t)d*2*H + ope*H + krow)*H + c]; }
    else      { v = W[((size_t)H + krow)*H + c]; }   // W[1]
    Bsw[t] = f2b(v);
}

// ---------------- depth-0 projections (bf16 out): sxw = src@W0, tyw = trg@W0
__global__ __launch_bounds__(256) void proj0b_kernel(
    const float* __restrict__ src, const float* __restrict__ trg,
    const float* __restrict__ W0, unsigned short* __restrict__ sxw,
    unsigned short* __restrict__ tyw)
{
    const int c = threadIdx.x;
    int gr0 = blockIdx.x * ROWSP;
    const float* inp; unsigned short* outp; int r0;
    if (gr0 < S * B) { inp = src; outp = sxw; r0 = gr0; }
    else             { inp = trg; outp = tyw; r0 = gr0 - S * B; }

    float acc[ROWSP];
#pragma unroll
    for (int rr = 0; rr < ROWSP; ++rr) acc[rr] = 0.f;
    for (int k = 0; k < H; ++k) {
        float wv = W0[k * H + c];
#pragma unroll
        for (int rr = 0; rr < ROWSP; ++rr)
            acc[rr] = fmaf(inp[(size_t)(r0 + rr) * H + k], wv, acc[rr]);
    }
#pragma unroll
    for (int rr = 0; rr < ROWSP; ++rr)
        outp[(size_t)(r0 + rr) * H + c] = f2b(acc[rr]);
}

__global__ __launch_bounds__(256) void zeroflags_kernel(int* flags, int n){
    int t = blockIdx.x * 256 + threadIdx.x;
    if (t < n) flags[t] = 0;
}

// ---------------- persistent dataflow grid kernel (R13 + per-wave polls) ---
// 192 blocks: 0..63 d0 (row=(blk&63)>>1, half=blk&1); 64..127 d1; 128..191
// proj. Each operand phase: per-wave poll -> stage 32KB -> 1 barrier -> 32
// MFMAs. LDS: 4 x 16KB slots (left=0,1; top=2,3; proj hx=0,1 hy=2,3).
__global__ __launch_bounds__(512, 2) void grid_kernel(
    const unsigned short* __restrict__ Bsw,
    const unsigned short* __restrict__ sxwb,
    const unsigned short* __restrict__ tywb,
    const float* __restrict__ bvec,
    float* __restrict__ out,
    int* __restrict__ flags)
{
    __shared__ unsigned short Alds[4 * 64 * 128];   // 64 KB
    char* AldsB = (char*)Alds;

    const int blk   = blockIdx.x;
    const int btyp  = blk >> 6;         // 0=d0, 1=d1, 2=proj
    const int i     = (blk & 63) >> 1;
    const int half  = blk & 1;
    const int c0    = half * 128;

    const int tid  = threadIdx.x;
    const int lane = tid & 63;
    const int wv   = tid >> 6;          // wave 0..7, owns 16 cols
    const int colq = lane & 15;
    const int hi   = lane >> 4;
    const int kk0  = hi * 8;
    const int col  = c0 + wv * 16 + colq;
    const int hi16 = hi * 16;
    const int lswz = (colq & 7) << 4;   // A-frag read swizzle (row&7 == colq&7)

    const int row64 = tid >> 3;         // staging row 0..63
    const int k4b   = (tid & 7) * 4;    // staging float4 base within 32
    const int swz   = (row64 & 7) << 4; // staging write swizzle

    int* flag0 = flags;
    int* flag1 = flags + S * T;
    int* flagg = flags + 2 * S * T;

    const size_t CH = (size_t)B * H;
#define OPTR(dd,ii,jj,ch) (out + ((((size_t)(dd)*S + (ii))*T + (jj))*2 + (ch)) * CH)

#define LOADC(LB, SP, KC) do { \
    const float* _p = (SP) + (size_t)row64 * H + (KC)*128 + k4b*4; \
    L[(LB)+0] = *(const float4*)(_p); \
    L[(LB)+1] = *(const float4*)(_p + 4); \
    L[(LB)+2] = *(const float4*)(_p + 8); \
    L[(LB)+3] = *(const float4*)(_p + 12); \
} while(0)

#define WRITEC(SLOT, LB) do { \
    _Pragma("unroll") \
    for (int _l = 0; _l < 4; ++_l) { \
        float4 _v = L[(LB)+_l]; \
        uint2 _u; \
        _u.x = f2b(_v.x) | ((unsigned)f2b(_v.y) << 16); \
        _u.y = f2b(_v.z) | ((unsigned)f2b(_v.w) << 16); \
        *(uint2*)(AldsB + (SLOT)*16384 + row64*256 + (((k4b+_l)*8) ^ swz)) = _u; \
    } \
} while(0)

#define AFRAG(SLOT, RT, KTL) (*(const s16x8*)(AldsB + (SLOT)*16384 + ((RT)*16 + colq)*256 + ((((KTL)*64) + hi16) ^ lswz)))

// one staged operand, 1 barrier: per-wave poll -> stage 32KB -> sync ->
// 32 MFMAs (kt0..3 from SLOT, kt4..7 from SLOT+1). ACC += A_op x BF.
#define OPPHASE2(SLOT, FP, TGT, SPTR, BF, ACC) do { \
    waitflag((FP), (TGT)); \
    const float* _sp = (SPTR); \
    LOADC(0, _sp, 0); \
    LOADC(4, _sp, 1); \
    WRITEC(SLOT, 0); \
    WRITEC((SLOT)+1, 4); \
    __syncthreads(); \
    _Pragma("unroll") \
    for (int _kt = 0; _kt < 8; ++_kt) { \
        const int _sl = (SLOT) + (_kt >> 2); \
        _Pragma("unroll") \
        for (int _rt = 0; _rt < 4; ++_rt) \
            ACC[_rt] = __builtin_amdgcn_mfma_f32_16x16x32_bf16(AFRAG(_sl,_rt,_kt & 3), BF[_kt], ACC[_rt], 0, 0, 0); \
    } \
} while(0)

    if (btyp == 0) {
        // ===================== depth-0 =====================
        s16x8 bfT[8], bfL[8];
#pragma unroll
        for (int kt = 0; kt < 8; ++kt) {
            int o = (kt * H + col) * 32 + kk0;
            bfT[kt] = *(const s16x8*)(Bsw + o);
            bfL[kt] = *(const s16x8*)(Bsw + (size_t)MSZ + o);
        }
        // xw is j-invariant: registers once
        unsigned short xwr[16];
        {
            const unsigned short* xwp = sxwb + (size_t)i * B * H;
#pragma unroll
            for (int rt = 0; rt < 4; ++rt)
#pragma unroll
                for (int q = 0; q < 4; ++q)
                    xwr[rt*4+q] = xwp[(size_t)(rt*16 + hi*4 + q) * H + col];
        }

        for (int j = 0; j < T; ++j) {
            // yw: issue loads before any polling
            unsigned short ywr[16];
            {
                const unsigned short* ywp = tywb + (size_t)j * B * H;
#pragma unroll
                for (int rt = 0; rt < 4; ++rt)
#pragma unroll
                    for (int q = 0; q < 4; ++q)
                        ywr[rt*4+q] = ywp[(size_t)(rt*16 + hi*4 + q) * H + col];
            }

            f32x4 acc[4];
#pragma unroll
            for (int rt = 0; rt < 4; ++rt) acc[rt] = (f32x4)(0.f);
            float4 L[8];

            if (j > 0)
                OPPHASE2(0, &flag0[i*T + (j-1)], 2, OPTR(0, i, j-1, 0), bfL, acc);
            if (i > 0)
                OPPHASE2(2, &flag0[(i-1)*T + j], 2, OPTR(0, i-1, j, 0), bfT, acc);

            float* ox = OPTR(0, i, j, 0);
            float* oy = OPTR(0, i, j, 1);
            const float bc = bvec[col];
#pragma unroll
            for (int rt = 0; rt < 4; ++rt)
#pragma unroll
                for (int q = 0; q < 4; ++q) {
                    int idx = rt*4 + q;
                    int row = rt*16 + hi*4 + q;
                    float rec = acc[rt][q] + bc;
                    float hx = tanh_fast(b2f(xwr[idx]) + rec);
                    float hy = tanh_fast(b2f(ywr[idx]) + rec);
                    __hip_atomic_store(&ox[row*H + col], hx, __ATOMIC_RELAXED, __HIP_MEMORY_SCOPE_AGENT);
                    __hip_atomic_store(&oy[row*H + col], hy, __ATOMIC_RELAXED, __HIP_MEMORY_SCOPE_AGENT);
                }

            asm volatile("s_waitcnt vmcnt(0)" ::: "memory");
            __syncthreads();
            if (tid == 0)
                __hip_atomic_fetch_add(&flag0[i*T + j], 1, __ATOMIC_RELEASE, __HIP_MEMORY_SCOPE_AGENT);
        }
    } else if (btyp == 1) {
        // ===================== depth-1 =====================
        s16x8 bfT[8], bfL[8];
#pragma unroll
        for (int kt = 0; kt < 8; ++kt) {
            int o = (kt * H + col) * 32 + kk0;
            bfT[kt] = *(const s16x8*)(Bsw + (size_t)2*MSZ + o);
            bfL[kt] = *(const s16x8*)(Bsw + (size_t)3*MSZ + o);
        }

        for (int j = 0; j < T; ++j) {
            // per-wave poll gg (stale), then px/py register loads (lane-
            // private; per-wave acquire orders them) — no barrier needed
            waitflag(&flagg[i*T + j], 2);
            float pxr[16], pyr[16];
            {
                const float* p0s = OPTR(1, i, j, 0);
                const float* p1s = OPTR(1, i, j, 1);
#pragma unroll
                for (int rt = 0; rt < 4; ++rt)
#pragma unroll
                    for (int q = 0; q < 4; ++q) {
                        int idx = rt*4 + q;
                        int row = rt*16 + hi*4 + q;
                        pxr[idx] = p0s[row*H + col];
                        pyr[idx] = p1s[row*H + col];
                    }
            }

            f32x4 ar[4];
#pragma unroll
            for (int rt = 0; rt < 4; ++rt) ar[rt] = (f32x4)(0.f);
            float4 L[8];

            if (j > 0)
                OPPHASE2(0, &flag1[i*T + (j-1)], 2, OPTR(1, i, j-1, 0), bfL, ar);
            if (i > 0)
                OPPHASE2(2, &flag1[(i-1)*T + j], 2, OPTR(1, i-1, j, 0), bfT, ar);

            // epilogue: hx1 (consumed) -> drain -> publish; hy1 (dead) after
            float recs[16];
            float* ox = OPTR(1, i, j, 0);
            const float bc = bvec[H + col];
#pragma unroll
            for (int rt = 0; rt < 4; ++rt)
#pragma unroll
                for (int q = 0; q < 4; ++q) {
                    int idx = rt*4 + q;
                    int row = rt*16 + hi*4 + q;
                    float rec = ar[rt][q] + bc;
                    recs[idx] = rec;
                    float hx = tanh_fast(pxr[idx] + rec);
                    __hip_atomic_store(&ox[row*H + col], hx, __ATOMIC_RELAXED, __HIP_MEMORY_SCOPE_AGENT);
                }
            asm volatile("s_waitcnt vmcnt(0)" ::: "memory");
            __syncthreads();
            if (tid == 0)
                __hip_atomic_fetch_add(&flag1[i*T + j], 1, __ATOMIC_RELEASE, __HIP_MEMORY_SCOPE_AGENT);

            float* oy = OPTR(1, i, j, 1);
#pragma unroll
            for (int rt = 0; rt < 4; ++rt)
#pragma unroll
                for (int q = 0; q < 4; ++q) {
                    int idx = rt*4 + q;
                    int row = rt*16 + hi*4 + q;
                    float hy = tanh_fast(pyr[idx] + recs[idx]);
                    __hip_atomic_store(&oy[row*H + col], hy, __ATOMIC_RELAXED, __HIP_MEMORY_SCOPE_AGENT);
                }
        }
    } else {
        // ===================== projection (no self-chain) =====================
        s16x8 bfW[8];
#pragma unroll
        for (int kt = 0; kt < 8; ++kt)
            bfW[kt] = *(const s16x8*)(Bsw + (size_t)4*MSZ + (kt * H + col) * 32 + kk0);

        for (int j = 0; j < T; ++j) {
            waitflag(&flag0[i*T + j], 2);   // per-wave poll, then stage

            f32x4 px[4], py[4];
#pragma unroll
            for (int rt = 0; rt < 4; ++rt) { px[rt] = (f32x4)(0.f); py[rt] = (f32x4)(0.f); }
            float4 L[16];

            const float* sHx0 = OPTR(0, i, j, 0);
            const float* sHy0 = OPTR(0, i, j, 1);
            LOADC(0,  sHx0, 0);
            LOADC(4,  sHx0, 1);
            LOADC(8,  sHy0, 0);
            LOADC(12, sHy0, 1);
            WRITEC(0, 0); WRITEC(1, 4); WRITEC(2, 8); WRITEC(3, 12);
            __syncthreads();
#pragma unroll
            for (int kt = 0; kt < 8; ++kt) {
                const int slx = (kt >> 2);
                const int sly = 2 + (kt >> 2);
#pragma unroll
                for (int rt = 0; rt < 4; ++rt) {
                    px[rt] = __builtin_amdgcn_mfma_f32_16x16x32_bf16(AFRAG(slx,rt,kt & 3), bfW[kt], px[rt], 0, 0, 0);
                    py[rt] = __builtin_amdgcn_mfma_f32_16x16x32_bf16(AFRAG(sly,rt,kt & 3), bfW[kt], py[rt], 0, 0, 0);
                }
            }

            float* p0 = OPTR(1, i, j, 0);
            float* p1 = OPTR(1, i, j, 1);
#pragma unroll
            for (int rt = 0; rt < 4; ++rt)
#pragma unroll
                for (int q = 0; q < 4; ++q) {
                    int row = rt*16 + hi*4 + q;
                    __hip_atomic_store(&p0[row*H + col], px[rt][q], __ATOMIC_RELAXED, __HIP_MEMORY_SCOPE_AGENT);
                    __hip_atomic_store(&p1[row*H + col], py[rt][q], __ATOMIC_RELAXED, __HIP_MEMORY_SCOPE_AGENT);
                }
            asm volatile("s_waitcnt vmcnt(0)" ::: "memory");
            __syncthreads();
            if (tid == 0)
                __hip_atomic_fetch_add(&flagg[i*T + j], 1, __ATOMIC_RELEASE, __HIP_MEMORY_SCOPE_AGENT);
        }
    }
#undef OPTR
#undef LOADC
#undef WRITEC
#undef AFRAG
#undef OPPHASE2
}

// =================== staged fallback (round-2 structure) ===================
__device__ inline s16x8 make_afrag(const float* __restrict__ M, int arow, int k0){
    const float* p = M + arow * H + k0;
    float4 x = *(const float4*)(p);
    float4 y = *(const float4*)(p + 4);
    s16x8 r;
    r[0]=(short)f2b(x.x); r[1]=(short)f2b(x.y); r[2]=(short)f2b(x.z); r[3]=(short)f2b(x.w);
    r[4]=(short)f2b(y.x); r[5]=(short)f2b(y.y); r[6]=(short)f2b(y.z); r[7]=(short)f2b(y.w);
    return r;
}

__global__ __launch_bounds__(64) void stage_kernel(
    const unsigned short* __restrict__ Bsw,
    const unsigned short* __restrict__ sxwb,
    const unsigned short* __restrict__ tywb,
    const float* __restrict__ bvec,
    float* __restrict__ out, int v)
{
    const int lane = threadIdx.x;
    const int cellid = blockIdx.x >> 2;
    const int stripe = blockIdx.x & 3;

    int ilo0 = (v > T-1) ? v-(T-1) : 0, ihi0 = (v < S-1) ? v : S-1;
    int n0 = (v <= S+T-2) ? (ihi0 - ilo0 + 1) : 0;
    if (n0 < 0) n0 = 0;
    int w1 = v - 1;
    int ilo1 = (w1 > T-1) ? w1-(T-1) : 0;

    int d, i, j;
    if (cellid < n0) { d = 0; i = ilo0 + cellid; j = v - i; }
    else             { d = 1; int q = cellid - n0; i = ilo1 + q; j = w1 - i; }

    const int r0   = stripe * 16;
    const int arow = r0 + (lane & 15);
    const int kk0  = (lane >> 4) * 8;
    const int colq = lane & 15;
    const int rowq = r0 + ((lane >> 4) << 2);

#define OUTB(dd,ii,jj,ch) (out + ((((size_t)(dd)*S + (ii))*T + (jj))*2 + (ch)) * (size_t)(B*H))

    if (d == 0) {
        f32x4 acc[16];
#pragma unroll
        for (int t = 0; t < 16; ++t) acc[t] = (f32x4)(0.f);
        if (i > 0) {
            const float* topM = OUTB(0, i-1, j, 0);
            const unsigned short* Bt = Bsw + 0*MSZ;
            for (int kt = 0; kt < 8; ++kt) {
                s16x8 a = make_afrag(topM, arow, kt*32 + kk0);
                const unsigned short* bp = Bt + (kt*H + colq)*32 + kk0;
#pragma unroll
                for (int ct = 0; ct < 16; ++ct)
                    acc[ct] = __builtin_amdgcn_mfma_f32_16x16x32_bf16(a, *(const s16x8*)(bp + ct*512), acc[ct], 0, 0, 0);
            }
        }
        if (j > 0) {
            const float* lftM = OUTB(0, i, j-1, 0);
            const unsigned short* Bl = Bsw + 1*MSZ;
            for (int kt = 0; kt < 8; ++kt) {
                s16x8 a = make_afrag(lftM, arow, kt*32 + kk0);
                const unsigned short* bp = Bl + (kt*H + colq)*32 + kk0;
#pragma unroll
                for (int ct = 0; ct < 16; ++ct)
                    acc[ct] = __builtin_amdgcn_mfma_f32_16x16x32_bf16(a, *(const s16x8*)(bp + ct*512), acc[ct], 0, 0, 0);
            }
        }
        const unsigned short* xwp = sxwb + (size_t)i * B * H;
        const unsigned short* ywp = tywb + (size_t)j * B * H;
        float* ox = OUTB(0, i, j, 0);
        float* oy = OUTB(0, i, j, 1);
#pragma unroll
        for (int ct = 0; ct < 16; ++ct) {
            int col = ct*16 + colq;
            float bc = bvec[col];
#pragma unroll
            for (int q = 0; q < 4; ++q) {
                int row = rowq + q;
                float rec = acc[ct][q] + bc;
                ox[row*H + col] = tanh_fast(b2f(xwp[row*H + col]) + rec);
                oy[row*H + col] = tanh_fast(b2f(ywp[row*H + col]) + rec);
            }
        }
    } else {
        const float* hx0 = OUTB(0, i, j, 0);
        const float* hy0 = OUTB(0, i, j, 1);
        const float* topM = (i > 0) ? OUTB(1, i-1, j, 0) : (const float*)0;
        const float* lftM = (j > 0) ? OUTB(1, i, j-1, 0) : (const float*)0;
        const unsigned short* BU1t = Bsw + 2*MSZ;
        const unsigned short* BU1l = Bsw + 3*MSZ;
        const unsigned short* BW1  = Bsw + 4*MSZ;
        float* ox = OUTB(1, i, j, 0);
        float* oy = OUTB(1, i, j, 1);

        for (int halfc = 0; halfc < 2; ++halfc) {
            f32x4 arr[8], axx[8], ayy[8];
#pragma unroll
            for (int t = 0; t < 8; ++t) { arr[t]=(f32x4)(0.f); axx[t]=(f32x4)(0.f); ayy[t]=(f32x4)(0.f); }
            const int bbase = halfc*4096 + colq*32 + kk0;

            for (int kt = 0; kt < 8; ++kt) {
                const int k0 = kt*32 + kk0;
                const int bofs = kt*H*32 + bbase;
                if (topM) {
                    s16x8 a = make_afrag(topM, arow, k0);
#pragma unroll
                    for (int ct = 0; ct < 8; ++ct)
                        arr[ct] = __builtin_amdgcn_mfma_f32_16x16x32_bf16(a, *(const s16x8*)(BU1t + bofs + ct*512), arr[ct], 0, 0, 0);
                }
                if (lftM) {
                    s16x8 a = make_afrag(lftM, arow, k0);
#pragma unroll
                    for (int ct = 0; ct < 8; ++ct)
                        arr[ct] = __builtin_amdgcn_mfma_f32_16x16x32_bf16(a, *(const s16x8*)(BU1l + bofs + ct*512), arr[ct], 0, 0, 0);
                }
                {
                    s16x8 a = make_afrag(hx0, arow, k0);
#pragma unroll
                    for (int ct = 0; ct < 8; ++ct)
                        axx[ct] = __builtin_amdgcn_mfma_f32_16x16x32_bf16(a, *(const s16x8*)(BW1 + bofs + ct*512), axx[ct], 0, 0, 0);
                }
                {
                    s16x8 a = make_afrag(hy0, arow, k0);
#pragma unroll
                    for (int ct = 0; ct < 8; ++ct)
                        ayy[ct] = __builtin_amdgcn_mfma_f32_16x16x32_bf16(a, *(const s16x8*)(BW1 + bofs + ct*512), ayy[ct], 0, 0, 0);
                }
            }
#pragma unroll
            for (int ct = 0; ct < 8; ++ct) {
                int col = halfc*128 + ct*16 + colq;
                float bc = bvec[H + col];
#pragma unroll
                for (int q = 0; q < 4; ++q) {
                    int row = rowq + q;
                    float rec = arr[ct][q] + bc;
                    ox[row*H + col] = tanh_fast(axx[ct][q] + rec);
                    oy[row*H + col] = tanh_fast(ayy[ct][q] + rec);
                }
            }
        }
    }
#undef OUTB
}

// ============================ host launcher ================================
extern "C" void kernel_launch(void* const* d_in, const int* in_sizes, int n_in,
                              void* d_out, int out_size, void* d_ws, size_t ws_size,
                              hipStream_t stream)
{
    const float* src = (const float*)d_in[0];
    const float* trg = (const float*)d_in[1];
    const float* W   = (const float*)d_in[2];
    const float* U   = (const float*)d_in[3];
    const float* b   = (const float*)d_in[4];
    float* out = (float*)d_out;

    const int nflags = 3 * S * T;
    const size_t need_stage   = (size_t)5*MSZ*2 + (size_t)2*S*B*H*2;
    const size_t need_persist = need_stage + (size_t)nflags*sizeof(int);

    unsigned short* Bsw  = (unsigned short*)d_ws;
    unsigned short* sxwb = Bsw + (size_t)5*MSZ;
    unsigned short* tywb = sxwb + (size_t)S*B*H;
    int* flags = (int*)(tywb + (size_t)S*B*H);

    if (ws_size >= need_persist) {
        prep_kernel<<<(5*MSZ + 255)/256, 256, 0, stream>>>(U, W, Bsw);
        proj0b_kernel<<<2*S*B/ROWSP, 256, 0, stream>>>(src, trg, W, sxwb, tywb);
        zeroflags_kernel<<<(nflags + 255)/256, 256, 0, stream>>>(flags, nflags);
        grid_kernel<<<192, 512, 0, stream>>>(Bsw, sxwb, tywb, b, out, flags);
        return;
    }

    // -------- staged fallback --------
    prep_kernel<<<(5*MSZ + 255)/256, 256, 0, stream>>>(U, W, Bsw);
    proj0b_kernel<<<2*S*B/ROWSP, 256, 0, stream>>>(src, trg, W, sxwb, tywb);
    for (int v = 0; v < S + T; ++v) {
        int ilo0 = (v > T-1) ? v-(T-1) : 0, ihi0 = (v < S-1) ? v : S-1;
        int n0 = (v <= S+T-2) ? (ihi0 - ilo0 + 1) : 0;
        if (n0 < 0) n0 = 0;
        int n1 = 0;
        int w1 = v - 1;
        if (w1 >= 0) {
            int ilo1 = (w1 > T-1) ? w1-(T-1) : 0, ihi1 = (w1 < S-1) ? w1 : S-1;
            n1 = ihi1 - ilo1 + 1;
        }
        stage_kernel<<<4*(n0+n1), 64, 0, stream>>>(Bsw, sxwb, tywb, b, out, v);
    }
}

// Round 16
// 619.792 us; speedup vs baseline: 1.7925x; 1.7925x over previous
//
#include <hip/hip_runtime.h>
#include <math.h>

#define S 32
#define T 32
#define B 64
#define H 256
#define MSZ 65536   // elements per swizzled bf16 matrix [8 kt][256 col][32 kk]
#define ROWSP 16

typedef __attribute__((ext_vector_type(8))) short s16x8;
typedef __attribute__((ext_vector_type(4))) float f32x4;

__device__ inline unsigned short f2b(float f){
    unsigned u = __builtin_bit_cast(unsigned, f);
    u += 0x7fffu + ((u >> 16) & 1u);          // RNE
    return (unsigned short)(u >> 16);
}
__device__ inline float b2f(unsigned short s){
    unsigned u = ((unsigned)s) << 16;
    return __builtin_bit_cast(float, u);
}
__device__ inline float tanh_fast(float x){
    float e = __builtin_amdgcn_exp2f(x * 2.8853900817779268f);
    float r = __builtin_amdgcn_rcpf(e + 1.0f);
    return fmaf(-2.0f, r, 1.0f);
}
__device__ inline void waitflag(int* f, int target){
    while (__hip_atomic_load(f, __ATOMIC_RELAXED, __HIP_MEMORY_SCOPE_AGENT) < target)
        __builtin_amdgcn_s_sleep(2);
    (void)__hip_atomic_load(f, __ATOMIC_ACQUIRE, __HIP_MEMORY_SCOPE_AGENT);
}

// ---------------- prep: swizzle U (both depths, top/left) + W[1] to bf16 ----
// Bsw[m][kt][c][kk] = M_m[kt*32+kk][c];  m: 0=U0t 1=U0l 2=U1t 3=U1l 4=W1
__global__ __launch_bounds__(256) void prep_kernel(
    const float* __restrict__ U, const float* __restrict__ W,
    unsigned short* __restrict__ Bsw)
{
    int t = blockIdx.x * 256 + threadIdx.x;
    if (t >= 5 * MSZ) return;
    int m  = t >> 16;
    int r  = t & 65535;
    int kt = r >> 13;
    int r2 = r & 8191;
    int c  = r2 >> 5;
    int kk = r2 & 31;
    int krow = kt * 32 + kk;
    float v;
    if (m < 4){ int d = m >> 1, ope = m & 1; v = U[((size_t)d*2*H + ope*H + krow)*H + c]; }
    else      { v = W[((size_t)H + krow)*H + c]; }   // W[1]
    Bsw[t] = f2b(v);
}

// ---------------- depth-0 projections (bf16 out): sxw = src@W0, tyw = trg@W0
__global__ __launch_bounds__(256) void proj0b_kernel(
    const float* __restrict__ src, const float* __restrict__ trg,
    const float* __restrict__ W0, unsigned short* __restrict__ sxw,
    unsigned short* __restrict__ tyw)
{
    const int c = threadIdx.x;
    int gr0 = blockIdx.x * ROWSP;
    const float* inp; unsigned short* outp; int r0;
    if (gr0 < S * B) { inp = src; outp = sxw; r0 = gr0; }
    else             { inp = trg; outp = tyw; r0 = gr0 - S * B; }

    float acc[ROWSP];
#pragma unroll
    for (int rr = 0; rr < ROWSP; ++rr) acc[rr] = 0.f;
    for (int k = 0; k < H; ++k) {
        float wv = W0[k * H + c];
#pragma unroll
        for (int rr = 0; rr < ROWSP; ++rr)
            acc[rr] = fmaf(inp[(size_t)(r0 + rr) * H + k], wv, acc[rr]);
    }
#pragma unroll
    for (int rr = 0; rr < ROWSP; ++rr)
        outp[(size_t)(r0 + rr) * H + c] = f2b(acc[rr]);
}

__global__ __launch_bounds__(256) void zeroflags_kernel(int* flags, int n){
    int t = blockIdx.x * 256 + threadIdx.x;
    if (t < n) flags[t] = 0;
}

// ---------------- persistent dataflow grid kernel (R13 champion) -----------
// 192 blocks: 0..63 d0 (row=(blk&63)>>1, half=blk&1); 64..127 d1; 128..191
// proj. Each operand phase: tid0 poll(1 barrier) -> full 32KB stage ->
// 1 barrier -> 32 MFMAs. LDS: 4 x 16KB slots.
__global__ __launch_bounds__(512, 2) void grid_kernel(
    const unsigned short* __restrict__ Bsw,
    const unsigned short* __restrict__ sxwb,
    const unsigned short* __restrict__ tywb,
    const float* __restrict__ bvec,
    float* __restrict__ out,
    int* __restrict__ flags)
{
    __shared__ unsigned short Alds[4 * 64 * 128];   // 64 KB
    char* AldsB = (char*)Alds;

    const int blk   = blockIdx.x;
    const int btyp  = blk >> 6;         // 0=d0, 1=d1, 2=proj
    const int i     = (blk & 63) >> 1;
    const int half  = blk & 1;
    const int c0    = half * 128;

    const int tid  = threadIdx.x;
    const int lane = tid & 63;
    const int wv   = tid >> 6;          // wave 0..7, owns 16 cols
    const int colq = lane & 15;
    const int hi   = lane >> 4;
    const int kk0  = hi * 8;
    const int col  = c0 + wv * 16 + colq;
    const int hi16 = hi * 16;
    const int lswz = (colq & 7) << 4;   // A-frag read swizzle (row&7 == colq&7)

    const int row64 = tid >> 3;         // staging row 0..63
    const int k4b   = (tid & 7) * 4;    // staging float4 base within 32
    const int swz   = (row64 & 7) << 4; // staging write swizzle

    int* flag0 = flags;
    int* flag1 = flags + S * T;
    int* flagg = flags + 2 * S * T;

    const size_t CH = (size_t)B * H;
#define OPTR(dd,ii,jj,ch) (out + ((((size_t)(dd)*S + (ii))*T + (jj))*2 + (ch)) * CH)

#define LOADC(LB, SP, KC) do { \
    const float* _p = (SP) + (size_t)row64 * H + (KC)*128 + k4b*4; \
    L[(LB)+0] = *(const float4*)(_p); \
    L[(LB)+1] = *(const float4*)(_p + 4); \
    L[(LB)+2] = *(const float4*)(_p + 8); \
    L[(LB)+3] = *(const float4*)(_p + 12); \
} while(0)

#define WRITEC(SLOT, LB) do { \
    _Pragma("unroll") \
    for (int _l = 0; _l < 4; ++_l) { \
        float4 _v = L[(LB)+_l]; \
        uint2 _u; \
        _u.x = f2b(_v.x) | ((unsigned)f2b(_v.y) << 16); \
        _u.y = f2b(_v.z) | ((unsigned)f2b(_v.w) << 16); \
        *(uint2*)(AldsB + (SLOT)*16384 + row64*256 + (((k4b+_l)*8) ^ swz)) = _u; \
    } \
} while(0)

#define AFRAG(SLOT, RT, KTL) (*(const s16x8*)(AldsB + (SLOT)*16384 + ((RT)*16 + colq)*256 + ((((KTL)*64) + hi16) ^ lswz)))

// one staged operand, 2 barriers: poll -> sync -> full 32KB stage -> sync ->
// 32 MFMAs (kt0..3 from SLOT, kt4..7 from SLOT+1). ACC += A_op x BF.
#define OPPHASE2(SLOT, FP, TGT, SPTR, BF, ACC) do { \
    if (tid == 0) waitflag((FP), (TGT)); \
    __syncthreads(); \
    const float* _sp = (SPTR); \
    LOADC(0, _sp, 0); \
    LOADC(4, _sp, 1); \
    WRITEC(SLOT, 0); \
    WRITEC((SLOT)+1, 4); \
    __syncthreads(); \
    _Pragma("unroll") \
    for (int _kt = 0; _kt < 8; ++_kt) { \
        const int _sl = (SLOT) + (_kt >> 2); \
        _Pragma("unroll") \
        for (int _rt = 0; _rt < 4; ++_rt) \
            ACC[_rt] = __builtin_amdgcn_mfma_f32_16x16x32_bf16(AFRAG(_sl,_rt,_kt & 3), BF[_kt], ACC[_rt], 0, 0, 0); \
    } \
} while(0)

    if (btyp == 0) {
        // ===================== depth-0 =====================
        s16x8 bfT[8], bfL[8];
#pragma unroll
        for (int kt = 0; kt < 8; ++kt) {
            int o = (kt * H + col) * 32 + kk0;
            bfT[kt] = *(const s16x8*)(Bsw + o);
            bfL[kt] = *(const s16x8*)(Bsw + (size_t)MSZ + o);
        }
        // xw is j-invariant: registers once
        unsigned short xwr[16];
        {
            const unsigned short* xwp = sxwb + (size_t)i * B * H;
#pragma unroll
            for (int rt = 0; rt < 4; ++rt)
#pragma unroll
                for (int q = 0; q < 4; ++q)
                    xwr[rt*4+q] = xwp[(size_t)(rt*16 + hi*4 + q) * H + col];
        }

        for (int j = 0; j < T; ++j) {
            // yw: issue loads before any polling
            unsigned short ywr[16];
            {
                const unsigned short* ywp = tywb + (size_t)j * B * H;
#pragma unroll
                for (int rt = 0; rt < 4; ++rt)
#pragma unroll
                    for (int q = 0; q < 4; ++q)
                        ywr[rt*4+q] = ywp[(size_t)(rt*16 + hi*4 + q) * H + col];
            }

            f32x4 acc[4];
#pragma unroll
            for (int rt = 0; rt < 4; ++rt) acc[rt] = (f32x4)(0.f);
            float4 L[8];

            if (j > 0)
                OPPHASE2(0, &flag0[i*T + (j-1)], 2, OPTR(0, i, j-1, 0), bfL, acc);
            if (i > 0)
                OPPHASE2(2, &flag0[(i-1)*T + j], 2, OPTR(0, i-1, j, 0), bfT, acc);

            float* ox = OPTR(0, i, j, 0);
            float* oy = OPTR(0, i, j, 1);
            const float bc = bvec[col];
#pragma unroll
            for (int rt = 0; rt < 4; ++rt)
#pragma unroll
                for (int q = 0; q < 4; ++q) {
                    int idx = rt*4 + q;
                    int row = rt*16 + hi*4 + q;
                    float rec = acc[rt][q] + bc;
                    float hx = tanh_fast(b2f(xwr[idx]) + rec);
                    float hy = tanh_fast(b2f(ywr[idx]) + rec);
                    __hip_atomic_store(&ox[row*H + col], hx, __ATOMIC_RELAXED, __HIP_MEMORY_SCOPE_AGENT);
                    __hip_atomic_store(&oy[row*H + col], hy, __ATOMIC_RELAXED, __HIP_MEMORY_SCOPE_AGENT);
                }

            asm volatile("s_waitcnt vmcnt(0)" ::: "memory");
            __syncthreads();
            if (tid == 0)
                __hip_atomic_fetch_add(&flag0[i*T + j], 1, __ATOMIC_RELEASE, __HIP_MEMORY_SCOPE_AGENT);
        }
    } else if (btyp == 1) {
        // ===================== depth-1 =====================
        s16x8 bfT[8], bfL[8];
#pragma unroll
        for (int kt = 0; kt < 8; ++kt) {
            int o = (kt * H + col) * 32 + kk0;
            bfT[kt] = *(const s16x8*)(Bsw + (size_t)2*MSZ + o);
            bfL[kt] = *(const s16x8*)(Bsw + (size_t)3*MSZ + o);
        }

        for (int j = 0; j < T; ++j) {
            // poll gg (stale: proj shadows d0, which runs ahead of us), then
            // issue px/py register loads early — latency hides under phases
            if (tid == 0) waitflag(&flagg[i*T + j], 2);
            __syncthreads();
            float pxr[16], pyr[16];
            {
                const float* p0s = OPTR(1, i, j, 0);
                const float* p1s = OPTR(1, i, j, 1);
#pragma unroll
                for (int rt = 0; rt < 4; ++rt)
#pragma unroll
                    for (int q = 0; q < 4; ++q) {
                        int idx = rt*4 + q;
                        int row = rt*16 + hi*4 + q;
                        pxr[idx] = p0s[row*H + col];
                        pyr[idx] = p1s[row*H + col];
                    }
            }

            f32x4 ar[4];
#pragma unroll
            for (int rt = 0; rt < 4; ++rt) ar[rt] = (f32x4)(0.f);
            float4 L[8];

            if (j > 0)
                OPPHASE2(0, &flag1[i*T + (j-1)], 2, OPTR(1, i, j-1, 0), bfL, ar);
            if (i > 0)
                OPPHASE2(2, &flag1[(i-1)*T + j], 2, OPTR(1, i-1, j, 0), bfT, ar);

            // epilogue: hx1 (consumed) -> drain -> publish; hy1 (dead) after
            float recs[16];
            float* ox = OPTR(1, i, j, 0);
            const float bc = bvec[H + col];
#pragma unroll
            for (int rt = 0; rt < 4; ++rt)
#pragma unroll
                for (int q = 0; q < 4; ++q) {
                    int idx = rt*4 + q;
                    int row = rt*16 + hi*4 + q;
                    float rec = ar[rt][q] + bc;
                    recs[idx] = rec;
                    float hx = tanh_fast(pxr[idx] + rec);
                    __hip_atomic_store(&ox[row*H + col], hx, __ATOMIC_RELAXED, __HIP_MEMORY_SCOPE_AGENT);
                }
            asm volatile("s_waitcnt vmcnt(0)" ::: "memory");
            __syncthreads();
            if (tid == 0)
                __hip_atomic_fetch_add(&flag1[i*T + j], 1, __ATOMIC_RELEASE, __HIP_MEMORY_SCOPE_AGENT);

            float* oy = OPTR(1, i, j, 1);
#pragma unroll
            for (int rt = 0; rt < 4; ++rt)
#pragma unroll
                for (int q = 0; q < 4; ++q) {
                    int idx = rt*4 + q;
                    int row = rt*16 + hi*4 + q;
                    float hy = tanh_fast(pyr[idx] + recs[idx]);
                    __hip_atomic_store(&oy[row*H + col], hy, __ATOMIC_RELAXED, __HIP_MEMORY_SCOPE_AGENT);
                }
        }
    } else {
        // ===================== projection (no self-chain) =====================
        s16x8 bfW[8];
#pragma unroll
        for (int kt = 0; kt < 8; ++kt)
            bfW[kt] = *(const s16x8*)(Bsw + (size_t)4*MSZ + (kt * H + col) * 32 + kk0);

        for (int j = 0; j < T; ++j) {
            if (tid == 0) waitflag(&flag0[i*T + j], 2);
            __syncthreads();

            f32x4 px[4], py[4];
#pragma unroll
            for (int rt = 0; rt < 4; ++rt) { px[rt] = (f32x4)(0.f); py[rt] = (f32x4)(0.f); }
            float4 L[16];

            const float* sHx0 = OPTR(0, i, j, 0);
            const float* sHy0 = OPTR(0, i, j, 1);
            LOADC(0,  sHx0, 0);
            LOADC(4,  sHx0, 1);
            LOADC(8,  sHy0, 0);
            LOADC(12, sHy0, 1);
            WRITEC(0, 0); WRITEC(1, 4); WRITEC(2, 8); WRITEC(3, 12);
            __syncthreads();
#pragma unroll
            for (int kt = 0; kt < 8; ++kt) {
                const int slx = (kt >> 2);
                const int sly = 2 + (kt >> 2);
#pragma unroll
                for (int rt = 0; rt < 4; ++rt) {
                    px[rt] = __builtin_amdgcn_mfma_f32_16x16x32_bf16(AFRAG(slx,rt,kt & 3), bfW[kt], px[rt], 0, 0, 0);
                    py[rt] = __builtin_amdgcn_mfma_f32_16x16x32_bf16(AFRAG(sly,rt,kt & 3), bfW[kt], py[rt], 0, 0, 0);
                }
            }

            float* p0 = OPTR(1, i, j, 0);
            float* p1 = OPTR(1, i, j, 1);
#pragma unroll
            for (int rt = 0; rt < 4; ++rt)
#pragma unroll
                for (int q = 0; q < 4; ++q) {
                    int row = rt*16 + hi*4 + q;
                    __hip_atomic_store(&p0[row*H + col], px[rt][q], __ATOMIC_RELAXED, __HIP_MEMORY_SCOPE_AGENT);
                    __hip_atomic_store(&p1[row*H + col], py[rt][q], __ATOMIC_RELAXED, __HIP_MEMORY_SCOPE_AGENT);
                }
            asm volatile("s_waitcnt vmcnt(0)" ::: "memory");
            __syncthreads();
            if (tid == 0)
                __hip_atomic_fetch_add(&flagg[i*T + j], 1, __ATOMIC_RELEASE, __HIP_MEMORY_SCOPE_AGENT);
        }
    }
#undef OPTR
#undef LOADC
#undef WRITEC
#undef AFRAG
#undef OPPHASE2
}

// =================== staged fallback (round-2 structure) ===================
__device__ inline s16x8 make_afrag(const float* __restrict__ M, int arow, int k0){
    const float* p = M + arow * H + k0;
    float4 x = *(const float4*)(p);
    float4 y = *(const float4*)(p + 4);
    s16x8 r;
    r[0]=(short)f2b(x.x); r[1]=(short)f2b(x.y); r[2]=(short)f2b(x.z); r[3]=(short)f2b(x.w);
    r[4]=(short)f2b(y.x); r[5]=(short)f2b(y.y); r[6]=(short)f2b(y.z); r[7]=(short)f2b(y.w);
    return r;
}

__global__ __launch_bounds__(64) void stage_kernel(
    const unsigned short* __restrict__ Bsw,
    const unsigned short* __restrict__ sxwb,
    const unsigned short* __restrict__ tywb,
    const float* __restrict__ bvec,
    float* __restrict__ out, int v)
{
    const int lane = threadIdx.x;
    const int cellid = blockIdx.x >> 2;
    const int stripe = blockIdx.x & 3;

    int ilo0 = (v > T-1) ? v-(T-1) : 0, ihi0 = (v < S-1) ? v : S-1;
    int n0 = (v <= S+T-2) ? (ihi0 - ilo0 + 1) : 0;
    if (n0 < 0) n0 = 0;
    int w1 = v - 1;
    int ilo1 = (w1 > T-1) ? w1-(T-1) : 0;

    int d, i, j;
    if (cellid < n0) { d = 0; i = ilo0 + cellid; j = v - i; }
    else             { d = 1; int q = cellid - n0; i = ilo1 + q; j = w1 - i; }

    const int r0   = stripe * 16;
    const int arow = r0 + (lane & 15);
    const int kk0  = (lane >> 4) * 8;
    const int colq = lane & 15;
    const int rowq = r0 + ((lane >> 4) << 2);

#define OUTB(dd,ii,jj,ch) (out + ((((size_t)(dd)*S + (ii))*T + (jj))*2 + (ch)) * (size_t)(B*H))

    if (d == 0) {
        f32x4 acc[16];
#pragma unroll
        for (int t = 0; t < 16; ++t) acc[t] = (f32x4)(0.f);
        if (i > 0) {
            const float* topM = OUTB(0, i-1, j, 0);
            const unsigned short* Bt = Bsw + 0*MSZ;
            for (int kt = 0; kt < 8; ++kt) {
                s16x8 a = make_afrag(topM, arow, kt*32 + kk0);
                const unsigned short* bp = Bt + (kt*H + colq)*32 + kk0;
#pragma unroll
                for (int ct = 0; ct < 16; ++ct)
                    acc[ct] = __builtin_amdgcn_mfma_f32_16x16x32_bf16(a, *(const s16x8*)(bp + ct*512), acc[ct], 0, 0, 0);
            }
        }
        if (j > 0) {
            const float* lftM = OUTB(0, i, j-1, 0);
            const unsigned short* Bl = Bsw + 1*MSZ;
            for (int kt = 0; kt < 8; ++kt) {
                s16x8 a = make_afrag(lftM, arow, kt*32 + kk0);
                const unsigned short* bp = Bl + (kt*H + colq)*32 + kk0;
#pragma unroll
                for (int ct = 0; ct < 16; ++ct)
                    acc[ct] = __builtin_amdgcn_mfma_f32_16x16x32_bf16(a, *(const s16x8*)(bp + ct*512), acc[ct], 0, 0, 0);
            }
        }
        const unsigned short* xwp = sxwb + (size_t)i * B * H;
        const unsigned short* ywp = tywb + (size_t)j * B * H;
        float* ox = OUTB(0, i, j, 0);
        float* oy = OUTB(0, i, j, 1);
#pragma unroll
        for (int ct = 0; ct < 16; ++ct) {
            int col = ct*16 + colq;
            float bc = bvec[col];
#pragma unroll
            for (int q = 0; q < 4; ++q) {
                int row = rowq + q;
                float rec = acc[ct][q] + bc;
                ox[row*H + col] = tanh_fast(b2f(xwp[row*H + col]) + rec);
                oy[row*H + col] = tanh_fast(b2f(ywp[row*H + col]) + rec);
            }
        }
    } else {
        const float* hx0 = OUTB(0, i, j, 0);
        const float* hy0 = OUTB(0, i, j, 1);
        const float* topM = (i > 0) ? OUTB(1, i-1, j, 0) : (const float*)0;
        const float* lftM = (j > 0) ? OUTB(1, i, j-1, 0) : (const float*)0;
        const unsigned short* BU1t = Bsw + 2*MSZ;
        const unsigned short* BU1l = Bsw + 3*MSZ;
        const unsigned short* BW1  = Bsw + 4*MSZ;
        float* ox = OUTB(1, i, j, 0);
        float* oy = OUTB(1, i, j, 1);

        for (int halfc = 0; halfc < 2; ++halfc) {
            f32x4 arr[8], axx[8], ayy[8];
#pragma unroll
            for (int t = 0; t < 8; ++t) { arr[t]=(f32x4)(0.f); axx[t]=(f32x4)(0.f); ayy[t]=(f32x4)(0.f); }
            const int bbase = halfc*4096 + colq*32 + kk0;

            for (int kt = 0; kt < 8; ++kt) {
                const int k0 = kt*32 + kk0;
                const int bofs = kt*H*32 + bbase;
                if (topM) {
                    s16x8 a = make_afrag(topM, arow, k0);
#pragma unroll
                    for (int ct = 0; ct < 8; ++ct)
                        arr[ct] = __builtin_amdgcn_mfma_f32_16x16x32_bf16(a, *(const s16x8*)(BU1t + bofs + ct*512), arr[ct], 0, 0, 0);
                }
                if (lftM) {
                    s16x8 a = make_afrag(lftM, arow, k0);
#pragma unroll
                    for (int ct = 0; ct < 8; ++ct)
                        arr[ct] = __builtin_amdgcn_mfma_f32_16x16x32_bf16(a, *(const s16x8*)(BU1l + bofs + ct*512), arr[ct], 0, 0, 0);
                }
                {
                    s16x8 a = make_afrag(hx0, arow, k0);
#pragma unroll
                    for (int ct = 0; ct < 8; ++ct)
                        axx[ct] = __builtin_amdgcn_mfma_f32_16x16x32_bf16(a, *(const s16x8*)(BW1 + bofs + ct*512), axx[ct], 0, 0, 0);
                }
                {
                    s16x8 a = make_afrag(hy0, arow, k0);
#pragma unroll
                    for (int ct = 0; ct < 8; ++ct)
                        ayy[ct] = __builtin_amdgcn_mfma_f32_16x16x32_bf16(a, *(const s16x8*)(BW1 + bofs + ct*512), ayy[ct], 0, 0, 0);
                }
            }
#pragma unroll
            for (int ct = 0; ct < 8; ++ct) {
                int col = halfc*128 + ct*16 + colq;
                float bc = bvec[H + col];
#pragma unroll
                for (int q = 0; q < 4; ++q) {
                    int row = rowq + q;
                    float rec = arr[ct][q] + bc;
                    ox[row*H + col] = tanh_fast(axx[ct][q] + rec);
                    oy[row*H + col] = tanh_fast(ayy[ct][q] + rec);
                }
            }
        }
    }
#undef OUTB
}

// ============================ host launcher ================================
extern "C" void kernel_launch(void* const* d_in, const int* in_sizes, int n_in,
                              void* d_out, int out_size, void* d_ws, size_t ws_size,
                              hipStream_t stream)
{
    const float* src = (const float*)d_in[0];
    const float* trg = (const float*)d_in[1];
    const float* W   = (const float*)d_in[2];
    const float* U   = (const float*)d_in[3];
    const float* b   = (const float*)d_in[4];
    float* out = (float*)d_out;

    const int nflags = 3 * S * T;
    const size_t need_stage   = (size_t)5*MSZ*2 + (size_t)2*S*B*H*2;
    const size_t need_persist = need_stage + (size_t)nflags*sizeof(int);

    unsigned short* Bsw  = (unsigned short*)d_ws;
    unsigned short* sxwb = Bsw + (size_t)5*MSZ;
    unsigned short* tywb = sxwb + (size_t)S*B*H;
    int* flags = (int*)(tywb + (size_t)S*B*H);

    if (ws_size >= need_persist) {
        prep_kernel<<<(5*MSZ + 255)/256, 256, 0, stream>>>(U, W, Bsw);
        proj0b_kernel<<<2*S*B/ROWSP, 256, 0, stream>>>(src, trg, W, sxwb, tywb);
        zeroflags_kernel<<<(nflags + 255)/256, 256, 0, stream>>>(flags, nflags);
        grid_kernel<<<192, 512, 0, stream>>>(Bsw, sxwb, tywb, b, out, flags);
        return;
    }

    // -------- staged fallback --------
    prep_kernel<<<(5*MSZ + 255)/256, 256, 0, stream>>>(U, W, Bsw);
    proj0b_kernel<<<2*S*B/ROWSP, 256, 0, stream>>>(src, trg, W, sxwb, tywb);
    for (int v = 0; v < S + T; ++v) {
        int ilo0 = (v > T-1) ? v-(T-1) : 0, ihi0 = (v < S-1) ? v : S-1;
        int n0 = (v <= S+T-2) ? (ihi0 - ilo0 + 1) : 0;
        if (n0 < 0) n0 = 0;
        int n1 = 0;
        int w1 = v - 1;
        if (w1 >= 0) {
            int ilo1 = (w1 > T-1) ? w1-(T-1) : 0, ihi1 = (w1 < S-1) ? w1 : S-1;
            n1 = ihi1 - ilo1 + 1;
        }
        stage_kernel<<<4*(n0+n1), 64, 0, stream>>>(Bsw, sxwb, tywb, b, out, v);
    }
}